// Round 2
// baseline (40644.766 us; speedup 1.0000x reference)
//
#include <hip/hip_runtime.h>

// ---------------- problem constants ----------------
#define PV 2048   // vocab
#define PE 768    // embed dim
#define PH 768    // hidden
#define PL 2      // layers
#define PB 256    // batch
#define PT 128    // seq len
#define PG 3072   // 4*H
#define PM 32768  // B*T rows (time-major: row r = t*PB + b)

// ---------------- helpers ----------------
__device__ __forceinline__ float b2f(unsigned short u) {
    return __uint_as_float(((unsigned int)u) << 16);
}
__device__ __forceinline__ unsigned short f2b(float f) {
    unsigned int x = __float_as_uint(f);
    x += 0x7fffu + ((x >> 16) & 1u);   // RNE
    return (unsigned short)(x >> 16);
}
__device__ __forceinline__ float sigm(float x) { return 1.f / (1.f + __expf(-x)); }
__device__ __forceinline__ float tanhfast(float x) {
    float t = __expf(2.f * x);
    return 1.f - 2.f / (t + 1.f);      // algebraically exact identity
}

// ---------------- zero / flood ----------------
__global__ __launch_bounds__(256) void zero_f32(float* __restrict__ p, int n4) {
    int i = blockIdx.x * 256 + threadIdx.x;
    if (i < n4) *(float4*)&p[(size_t)i * 4] = make_float4(0.f, 0.f, 0.f, 0.f);
}
// diagnostic: ws too small -> absmax ~= 2048 signature
__global__ __launch_bounds__(256) void flood_f32(float* __restrict__ p, size_t n) {
    size_t i = (size_t)blockIdx.x * 256 + threadIdx.x;
    size_t stride = (size_t)gridDim.x * 256;
    for (; i < n; i += stride) p[i] = 2048.0f;
}

// ---------------- embedding gather (f32 table -> bf16 seq, time-major) ----------------
// out[r][e] = emb[tok[b*T+t]][e],  r = t*PB + b
__global__ __launch_bounds__(256) void embed_kernel(const int* __restrict__ tok,
                                                    const float* __restrict__ emb,
                                                    unsigned short* __restrict__ out) {
    int idx = blockIdx.x * 256 + threadIdx.x;   // float4 id; grid covers PM*PE/4 exactly
    int e4 = idx % (PE / 4);
    int r  = idx / (PE / 4);
    int b = r & (PB - 1);
    int t = r >> 8;                              // PB = 256
    int token = tok[b * PT + t];
    float4 v = *(const float4*)&emb[(size_t)token * PE + e4 * 4];
    ushort4 o = make_ushort4(f2b(v.x), f2b(v.y), f2b(v.z), f2b(v.w));
    *(ushort4*)&out[(size_t)r * PE + e4 * 4] = o;
}

// ---------------- NT GEMM: C[M,N] = A_bf16[M,K] * Bw_f32[N,K]^T (+bias) ----------------
// 128x128 tile, BK=16, 256 threads, 8x8 micro-tile.
// MODE 0: C = f32 xg, add bias0[n]+bias1[n].
// MODE 1: C = f32 d_out with row remap r=t*PB+b -> (b*PT+t)*PV + n, add bias0[n].
template <int MODE>
__global__ __launch_bounds__(256)
void gemm_bf16a(const unsigned short* __restrict__ A,
                const float* __restrict__ Bw,
                float* __restrict__ C,
                const float* __restrict__ bias0,
                const float* __restrict__ bias1,
                int N, int K) {
    __shared__ float As[16][132];
    __shared__ float Bs[16][132];
    const int n0 = blockIdx.x * 128;
    const int m0 = blockIdx.y * 128;
    const int tid = threadIdx.x;
    const int tx = tid & 15, ty = tid >> 4;
    float acc[8][8] = {};
    for (int k0 = 0; k0 < K; k0 += 16) {
        {   // A tile: 128 rows x 16 k of bf16; each thread 8 contiguous bf16 (16B)
            int row = tid >> 1, kk = (tid & 1) * 8;
            const unsigned short* ap = A + (size_t)(m0 + row) * K + k0 + kk;
            uint4 raw = *(const uint4*)ap;
            const unsigned short* pu = (const unsigned short*)&raw;
#pragma unroll
            for (int i = 0; i < 8; ++i) As[kk + i][row] = b2f(pu[i]);
        }
#pragma unroll
        for (int u = 0; u < 2; ++u) {   // B tile: 128 rows x 16 k f32
            int idx = u * 256 + tid;
            int row = idx >> 2, kk = (idx & 3) * 4;
            float4 v = *(const float4*)&Bw[(size_t)(n0 + row) * K + k0 + kk];
            Bs[kk + 0][row] = v.x; Bs[kk + 1][row] = v.y;
            Bs[kk + 2][row] = v.z; Bs[kk + 3][row] = v.w;
        }
        __syncthreads();
#pragma unroll
        for (int k = 0; k < 16; ++k) {
            float a[8], b[8];
#pragma unroll
            for (int i = 0; i < 4; ++i) {
                a[i]     = As[k][ty * 4 + i];
                a[4 + i] = As[k][64 + ty * 4 + i];
                b[i]     = Bs[k][tx * 4 + i];
                b[4 + i] = Bs[k][64 + tx * 4 + i];
            }
#pragma unroll
            for (int i = 0; i < 8; ++i)
#pragma unroll
                for (int j = 0; j < 8; ++j) acc[i][j] += a[i] * b[j];
        }
        __syncthreads();
    }
    // epilogue
#pragma unroll
    for (int i = 0; i < 8; ++i) {
        int mi = m0 + ((i < 4) ? (ty * 4 + i) : (64 + ty * 4 + (i - 4)));
#pragma unroll
        for (int half = 0; half < 2; ++half) {
            int nj = n0 + half * 64 + tx * 4;
            if (MODE == 0) {
                float4 o;
                o.x = acc[i][half * 4 + 0] + bias0[nj + 0] + bias1[nj + 0];
                o.y = acc[i][half * 4 + 1] + bias0[nj + 1] + bias1[nj + 1];
                o.z = acc[i][half * 4 + 2] + bias0[nj + 2] + bias1[nj + 2];
                o.w = acc[i][half * 4 + 3] + bias0[nj + 3] + bias1[nj + 3];
                *(float4*)&C[(size_t)mi * N + nj] = o;
            } else {
                int b = mi & (PB - 1), t = mi >> 8;
                size_t base = ((size_t)b * PT + t) * PV + nj;
                float4 o;
                o.x = acc[i][half * 4 + 0] + bias0[nj + 0];
                o.y = acc[i][half * 4 + 1] + bias0[nj + 1];
                o.z = acc[i][half * 4 + 2] + bias0[nj + 2];
                o.w = acc[i][half * 4 + 3] + bias0[nj + 3];
                *(float4*)&C[base] = o;
            }
        }
    }
}

// ---------------- one LSTM timestep, fused (g = xg_t + h@Whh^T; gates; h,c update) ----
// grid (PH/32, PB/32) = (24,8); 256 threads; per thread 2b x 2j x 4 gates.
// h ping-pong (h_in != h_out, race-free); c in place (thread-private slots).
__global__ __launch_bounds__(256)
void lstm_step(const float* __restrict__ xg_t,       // [PB, PG] slab for this t
               const float* __restrict__ Whh,        // [PG, PH]
               const float* __restrict__ h_in,       // [PB, PH]
               float* __restrict__ h_out,            // [PB, PH]
               float* __restrict__ c_io,             // [PB, PH]
               unsigned short* __restrict__ seq_out) // [PB, PH] bf16 (row slab at t*PB)
{
    __shared__ float Hs[16][33];
    __shared__ float Ws[4][16][33];
    const int jt = blockIdx.x * 32;
    const int bt = blockIdx.y * 32;
    const int tid = threadIdx.x;
    const int txj = tid & 15, tyb = tid >> 4;
    float acc[4][2][2] = {};
    for (int k0 = 0; k0 < PH; k0 += 16) {
        if (tid < 128) {   // Hs: 32 b x 16 k
            int b = tid >> 2, kk = (tid & 3) * 4;
            float4 v = *(const float4*)&h_in[(size_t)(bt + b) * PH + k0 + kk];
            Hs[kk + 0][b] = v.x; Hs[kk + 1][b] = v.y;
            Hs[kk + 2][b] = v.z; Hs[kk + 3][b] = v.w;
        }
#pragma unroll
        for (int u = 0; u < 2; ++u) {   // Ws: 4g x 32 j x 16 k
            int idx = u * 256 + tid;
            int kk = (idx & 3) * 4;
            int j = (idx >> 2) & 31;
            int g = idx >> 7;
            float4 v = *(const float4*)&Whh[((size_t)g * PH + jt + j) * PH + k0 + kk];
            Ws[g][kk + 0][j] = v.x; Ws[g][kk + 1][j] = v.y;
            Ws[g][kk + 2][j] = v.z; Ws[g][kk + 3][j] = v.w;
        }
        __syncthreads();
#pragma unroll
        for (int k = 0; k < 16; ++k) {
            float hr0 = Hs[k][tyb * 2 + 0], hr1 = Hs[k][tyb * 2 + 1];
#pragma unroll
            for (int g = 0; g < 4; ++g) {
                float w0 = Ws[g][k][txj * 2 + 0], w1 = Ws[g][k][txj * 2 + 1];
                acc[g][0][0] += hr0 * w0; acc[g][0][1] += hr0 * w1;
                acc[g][1][0] += hr1 * w0; acc[g][1][1] += hr1 * w1;
            }
        }
        __syncthreads();
    }
#pragma unroll
    for (int i = 0; i < 2; ++i) {
        int b = bt + tyb * 2 + i;
        const float* xrow = xg_t + (size_t)b * PG;
#pragma unroll
        for (int j = 0; j < 2; ++j) {
            int jj = jt + txj * 2 + j;
            float pi = acc[0][i][j] + xrow[jj];            // gate order: i,f,g,o
            float pf = acc[1][i][j] + xrow[PH + jj];
            float pg = acc[2][i][j] + xrow[2 * PH + jj];
            float po = acc[3][i][j] + xrow[3 * PH + jj];
            float si = sigm(pi), sf = sigm(pf), so = sigm(po);
            float cn = sf * c_io[(size_t)b * PH + jj] + si * tanhfast(pg);
            float hn = so * tanhfast(cn);
            c_io[(size_t)b * PH + jj] = cn;
            h_out[(size_t)b * PH + jj] = hn;
            seq_out[(size_t)b * PH + jj] = f2b(hn);
        }
    }
}

// ---------------- host orchestration ----------------
extern "C" void kernel_launch(void* const* d_in, const int* in_sizes, int n_in,
                              void* d_out, int out_size, void* d_ws, size_t ws_size,
                              hipStream_t stream) {
    const int*   src     = (const int*)d_in[0];
    const int*   trg     = (const int*)d_in[1];
    const float* enc_emb = (const float*)d_in[2];
    const float* enc_Wih = (const float*)d_in[3];
    const float* enc_Whh = (const float*)d_in[4];
    const float* enc_bih = (const float*)d_in[5];
    const float* enc_bhh = (const float*)d_in[6];
    const float* dec_emb = (const float*)d_in[7];
    const float* dec_Wih = (const float*)d_in[8];
    const float* dec_Whh = (const float*)d_in[9];
    const float* dec_bih = (const float*)d_in[10];
    const float* dec_bhh = (const float*)d_in[11];
    const float* fc_W    = (const float*)d_in[12];
    const float* fc_b    = (const float*)d_in[13];

    // d_out is FLOAT32, PM*PV elems = 268 MB. Its first 100.6 MB double as
    // scratch for the two bf16 sequence ping-pong buffers (2 x 50.3 MB);
    // fully overwritten by the final logits GEMM.
    unsigned short* bufA = (unsigned short*)d_out;
    unsigned short* bufB = bufA + (size_t)PM * PH;

    // ws layout: [xg/copy region (reg_bytes)] [hst (PL*2*B*H f32)] [cst (PL*B*H f32)]
    const size_t copy_bytes  = (size_t)PM * PH * 2;                  // 50,331,648
    const size_t state_f     = (size_t)PL * 2 * PB * PH + (size_t)PL * PB * PH;
    const size_t state_bytes = state_f * 4;
    int Tc;
    if (ws_size >= (size_t)32 * PB * PG * 4 + state_bytes)      Tc = 32;  // 105.4 MB
    else if (ws_size >= copy_bytes + state_bytes)               Tc = 16;  // 55.1 MB
    else {
        flood_f32<<<dim3(2048), dim3(256), 0, stream>>>((float*)d_out, (size_t)out_size);
        return;   // ws too small: emit absmax ~= 2048 diagnostic signature
    }
    size_t xb0 = (size_t)Tc * PB * PG * 4;
    size_t reg_bytes = xb0 > copy_bytes ? xb0 : copy_bytes;
    float* xg  = (float*)d_ws;
    float* hst = (float*)((char*)d_ws + reg_bytes);          // [PL][2][PB,PH]
    float* cst = hst + (size_t)PL * 2 * PB * PH;             // [PL][PB,PH]

    const dim3 blk(256);
    const int BH = PB * PH;

    // zero h/c states (contiguous)
    {
        int n4 = (int)(state_f / 4);
        zero_f32<<<dim3((n4 + 255) / 256), blk, 0, stream>>>(hst, n4);
    }

    unsigned short *sin = bufA, *sout = bufB;
    for (int phase = 0; phase < 2; ++phase) {
        const float* Wih_all = phase ? dec_Wih : enc_Wih;
        const float* Whh_all = phase ? dec_Whh : enc_Whh;
        const float* bih_all = phase ? dec_bih : enc_bih;
        const float* bhh_all = phase ? dec_bhh : enc_bhh;
        embed_kernel<<<dim3(PM * PE / 4 / 256), blk, 0, stream>>>(
            phase ? trg : src, phase ? dec_emb : enc_emb, bufA);
        sin = bufA; sout = bufB;
        for (int l = 0; l < PL; ++l) {
            const float* Wih = Wih_all + (size_t)l * PG * PE;
            const float* Whh = Whh_all + (size_t)l * PG * PH;
            const float* bih = bih_all + (size_t)l * PG;
            const float* bhh = bhh_all + (size_t)l * PG;
            for (int c = 0; c < PT / Tc; ++c) {
                gemm_bf16a<0><<<dim3(PG / 128, Tc * PB / 128), blk, 0, stream>>>(
                    sin + (size_t)c * Tc * PB * PE, Wih, xg, bih, bhh, PG, PE);
                for (int tt = 0; tt < Tc; ++tt) {
                    int t = c * Tc + tt, p = t & 1;
                    lstm_step<<<dim3(PH / 32, PB / 32), blk, 0, stream>>>(
                        xg + (size_t)tt * PB * PG, Whh,
                        hst + (size_t)(l * 2 + p) * BH,
                        hst + (size_t)(l * 2 + (1 - p)) * BH,
                        cst + (size_t)l * BH,
                        sout + (size_t)t * BH);
                }
            }
            unsigned short* tmp = sin; sin = sout; sout = tmp;
        }
    }
    // sin now holds the final decoder layer output (bf16, [PM,PH]) == bufA.
    // Copy it into ws so the logits GEMM (which overwrites ALL of d_out,
    // including bufA) reads from a disjoint region.
    hipMemcpyAsync((void*)xg, (const void*)sin, copy_bytes,
                   hipMemcpyDeviceToDevice, stream);
    gemm_bf16a<1><<<dim3(PV / 128, PM / 128), blk, 0, stream>>>(
        (const unsigned short*)xg, fc_W, (float*)d_out, fc_b,
        (const float*)nullptr, PV, PH);
}